// Round 1
// baseline (39341.898 us; speedup 1.0000x reference)
//
#include <hip/hip_runtime.h>
#include <stdint.h>

#define RES    1024
#define INPD   16
#define OUTD   8
#define BATCH  32
#define SEQ    4096
#define COLCAP 192            // padded max nnz per row (mean ~102, huge headroom)
#define NCHUNK (COLCAP / 8)   // 24 chunks of 8 nonzeros

// ws layout:
//   idx: uint32 [NCHUNK][RES][8]  column index into h (0..1023)
//   val: float  [NCHUNK][RES][8]
//   nnz: uint32 [RES]
#define IDX_BYTES (NCHUNK * RES * 8 * 4)   // 786432

// ---------------------------------------------------------------------------
// Preprocess: compact each row of W_res (exact zeros from the connectivity
// mask) into the padded chunked layout. One wave per row.
// ---------------------------------------------------------------------------
__global__ __launch_bounds__(64) void esn_prep(const float* __restrict__ W,
                                               uint32_t* __restrict__ idx,
                                               float* __restrict__ val,
                                               uint32_t* __restrict__ nnz) {
  const int r    = blockIdx.x;
  const int lane = threadIdx.x;  // 0..63
  const float* row = W + (size_t)r * RES;

  uint32_t base = 0;
  for (int c = 0; c < RES / 64; ++c) {
    float v = row[c * 64 + lane];
    unsigned long long m = __ballot(v != 0.0f);
    uint32_t pos = (uint32_t)__popcll(m & ((1ull << lane) - 1ull));
    if (v != 0.0f) {
      uint32_t n = base + pos;
      if (n < COLCAP) {
        uint32_t off = (n >> 3) * (RES * 8) + (uint32_t)r * 8 + (n & 7u);
        idx[off] = (uint32_t)(c * 64 + lane);
        val[off] = v;
      }
    }
    base += (uint32_t)__popcll(m);
  }
  // zero-pad the tail so the scan kernel can overread full 8-chunks safely
  for (uint32_t n = base + (uint32_t)lane; n < COLCAP; n += 64) {
    uint32_t off = (n >> 3) * (RES * 8) + (uint32_t)r * 8 + (n & 7u);
    idx[off] = 0;
    val[off] = 0.0f;
  }
  if (lane == 0) nnz[r] = (base < COLCAP) ? base : (uint32_t)COLCAP;
}

// ---------------------------------------------------------------------------
// Scan: one block per batch element. h double-buffered in LDS; one
// __syncthreads per timestep. Fused input projection (W_in row in VGPRs,
// x_t staged in LDS) and fused output projection (wave butterfly reduce,
// cross-wave combine for step t-1 overlapped into step t).
// ---------------------------------------------------------------------------
__global__ __launch_bounds__(1024) void esn_scan(
    const float* __restrict__ x, const float* __restrict__ state,
    const float* __restrict__ Win, const float* __restrict__ Woutw,
    const float* __restrict__ Woutb,
    const uint32_t* __restrict__ idx, const float* __restrict__ val,
    const uint32_t* __restrict__ nnz,
    float* __restrict__ out) {
  __shared__ float  hbuf[2][RES];
  __shared__ float4 xbuf[2][INPD / 4];
  __shared__ float  wpart[2][16][OUTD];

  const int b    = blockIdx.x;
  const int tid  = threadIdx.x;   // == row index r
  const int wave = tid >> 6;
  const int lane = tid & 63;

  // per-row weights in registers
  const float4* winp = (const float4*)(Win + (size_t)tid * INPD);
  const float4 w0 = winp[0], w1 = winp[1], w2 = winp[2], w3 = winp[3];
  float wout[OUTD];
#pragma unroll
  for (int o = 0; o < OUTD; ++o) wout[o] = Woutw[o * RES + tid];
  const float bia = (tid < OUTD) ? Woutb[tid] : 0.0f;

  float hreg = state[(size_t)b * RES + tid];
  hbuf[0][tid] = hreg;
  const int nc = (int)((nnz[tid] + 7u) >> 3);

  const float* xrow = x + (size_t)b * SEQ * INPD;
  if (tid < INPD / 4) xbuf[0][tid] = ((const float4*)xrow)[tid];

  const uint32_t* ip = idx + (size_t)tid * 8;
  const float*    vp = val + (size_t)tid * 8;
  float* finals = out + (size_t)BATCH * SEQ * OUTD;

  __syncthreads();

  for (int t = 0; t < SEQ; ++t) {
    const int par = t & 1;

    // phase-2 of previous step: combine wave partials, store 8 outputs
    if (t > 0 && tid < OUTD) {
      float s = bia;
#pragma unroll
      for (int w = 0; w < 16; ++w) s += wpart[par ^ 1][w][tid];
      out[((size_t)b * SEQ + (t - 1)) * OUTD + tid] = s;
    }
    // stage x for step t+1 (wave 1, different LDS slot -> race-free)
    if (tid >= 64 && tid < 64 + INPD / 4 && t + 1 < SEQ) {
      xbuf[par ^ 1][tid - 64] = ((const float4*)(xrow + (size_t)(t + 1) * INPD))[tid - 64];
    }

    // input projection: dot(x_t, W_in[r,:])
    const float4 xa = xbuf[par][0], xb = xbuf[par][1];
    const float4 xc = xbuf[par][2], xd = xbuf[par][3];
    float a0 = 0.0f, a1 = 0.0f, a2 = 0.0f, a3 = 0.0f;
    a0 = fmaf(xa.x, w0.x, a0); a1 = fmaf(xa.y, w0.y, a1);
    a2 = fmaf(xa.z, w0.z, a2); a3 = fmaf(xa.w, w0.w, a3);
    a0 = fmaf(xb.x, w1.x, a0); a1 = fmaf(xb.y, w1.y, a1);
    a2 = fmaf(xb.z, w1.z, a2); a3 = fmaf(xb.w, w1.w, a3);
    a0 = fmaf(xc.x, w2.x, a0); a1 = fmaf(xc.y, w2.y, a1);
    a2 = fmaf(xc.z, w2.z, a2); a3 = fmaf(xc.w, w2.w, a3);
    a0 = fmaf(xd.x, w3.x, a0); a1 = fmaf(xd.y, w3.y, a1);
    a2 = fmaf(xd.z, w3.z, a2); a3 = fmaf(xd.w, w3.w, a3);

    // sparse recurrent dot: acc += sum_k W[r,k] * h[k]
    const float* hcur = hbuf[par];
    for (int c = 0; c < nc; ++c) {
      const size_t o8 = (size_t)c * (RES * 8);
      const uint4  i4a = *(const uint4*)(ip + o8);
      const uint4  i4b = *(const uint4*)(ip + o8 + 4);
      const float4 v4a = *(const float4*)(vp + o8);
      const float4 v4b = *(const float4*)(vp + o8 + 4);
      a0 = fmaf(v4a.x, hcur[i4a.x], a0);
      a1 = fmaf(v4a.y, hcur[i4a.y], a1);
      a2 = fmaf(v4a.z, hcur[i4a.z], a2);
      a3 = fmaf(v4a.w, hcur[i4a.w], a3);
      a0 = fmaf(v4b.x, hcur[i4b.x], a0);
      a1 = fmaf(v4b.y, hcur[i4b.y], a1);
      a2 = fmaf(v4b.z, hcur[i4b.z], a2);
      a3 = fmaf(v4b.w, hcur[i4b.w], a3);
    }
    const float acc = (a0 + a1) + (a2 + a3);

    // tanh via exp2:  tanh(x) = 1 - 2/(e^{2x}+1)
    const float e  = exp2f(acc * 2.885390081777927f);   // 2*log2(e)
    const float th = 1.0f - 2.0f * __builtin_amdgcn_rcpf(e + 1.0f);
    const float hn = fmaf(0.7f, th, 0.3f * hreg);
    hreg = hn;
    hbuf[par ^ 1][tid] = hn;

    // output partials: po[o] = sum over this wave's rows of hn * W_out[o,r]
    float po[OUTD];
#pragma unroll
    for (int o = 0; o < OUTD; ++o) po[o] = hn * wout[o];
#pragma unroll
    for (int d2 = 1; d2 < 64; d2 <<= 1) {
#pragma unroll
      for (int o = 0; o < OUTD; ++o) po[o] += __shfl_xor(po[o], d2);
    }
    if (lane == 0) {
#pragma unroll
      for (int o = 0; o < OUTD; ++o) wpart[par][wave][o] = po[o];
    }

    __syncthreads();
  }

  // tail: outputs for t = SEQ-1 (its partials are in wpart[(SEQ-1)&1 == 1])
  if (tid < OUTD) {
    float s = bia;
#pragma unroll
    for (int w = 0; w < 16; ++w) s += wpart[1][w][tid];
    out[((size_t)b * SEQ + (SEQ - 1)) * OUTD + tid] = s;
  }
  // final state
  finals[(size_t)b * RES + tid] = hreg;
}

// ---------------------------------------------------------------------------
extern "C" void kernel_launch(void* const* d_in, const int* in_sizes, int n_in,
                              void* d_out, int out_size, void* d_ws, size_t ws_size,
                              hipStream_t stream) {
  const float* x     = (const float*)d_in[0];
  const float* state = (const float*)d_in[1];
  const float* Win   = (const float*)d_in[2];
  const float* Wres  = (const float*)d_in[3];
  const float* Woutw = (const float*)d_in[4];
  const float* Woutb = (const float*)d_in[5];
  float* out = (float*)d_out;

  uint8_t*  ws  = (uint8_t*)d_ws;
  uint32_t* idx = (uint32_t*)ws;
  float*    val = (float*)(ws + IDX_BYTES);
  uint32_t* nnz = (uint32_t*)(ws + 2 * (size_t)IDX_BYTES);

  esn_prep<<<RES, 64, 0, stream>>>(Wres, idx, val, nnz);
  esn_scan<<<BATCH, RES, 0, stream>>>(x, state, Win, Woutw, Woutb,
                                      idx, val, nnz, out);
}